// Round 3
// baseline (311.924 us; speedup 1.0000x reference)
//
#include <hip/hip_runtime.h>

// j = 1 - log10(1024*|x-y| + 1), elementwise over float32 tensors.
// shape (8,16,4096,64) = 33,554,432 f32 elements per tensor (134.2 MB each).
//
// R3 post-mortem: nontemporal stores REGRESSED (105 -> 119 us) and did not
// move FETCH_SIZE -> reverted. The ~50% input L3 hit is stable regardless.
//
// R4 theory: baseline ran 131,072 single-shot workgroups, each moving only
// 12 KB. Workgroup dispatch/setup overhead serializes against the memory
// stream (2.55 TB/s HBM << 6.3 TB/s ceiling, VALUBusy 4.7%, no conflicts).
// Fix per Guideline 11: grid-stride loop, 2048 blocks (8/CU), 16 float4s per
// thread, unroll 4 for memory-level parallelism within each wave.
// Prediction: FETCH/WRITE unchanged, dispatch 105 -> ~70-85 us.

typedef float f32x4 __attribute__((ext_vector_type(4)));

__device__ __forceinline__ float j_elem(float xv, float yv) {
    float d = xv - yv;
    // sqrt(1024^2 * d^2) == 1024 * |d|
    float dist = 1024.0f * fabsf(d);
    // log10(v) = log2(v) * log10(2); v_log_f32 accuracy ~1 ulp, threshold 5.75e-2
    return 1.0f - 0.30102999566398120f * __log2f(dist + 1.0f);
}

__global__ __launch_bounds__(256) void j_gridstride_kernel(const f32x4* __restrict__ x,
                                                           const f32x4* __restrict__ y,
                                                           f32x4* __restrict__ out,
                                                           int nvec) {
    int tid = blockIdx.x * blockDim.x + threadIdx.x;
    int stride = gridDim.x * blockDim.x;
    #pragma unroll 4
    for (int i = tid; i < nvec; i += stride) {
        f32x4 xv = x[i];
        f32x4 yv = y[i];
        f32x4 ov;
        ov.x = j_elem(xv.x, yv.x);
        ov.y = j_elem(xv.y, yv.y);
        ov.z = j_elem(xv.z, yv.z);
        ov.w = j_elem(xv.w, yv.w);
        out[i] = ov;
    }
}

__global__ __launch_bounds__(256) void j_tail_kernel(const float* __restrict__ x,
                                                     const float* __restrict__ y,
                                                     float* __restrict__ out,
                                                     int start, int n) {
    int i = start + blockIdx.x * blockDim.x + threadIdx.x;
    if (i >= n) return;
    out[i] = j_elem(x[i], y[i]);
}

extern "C" void kernel_launch(void* const* d_in, const int* in_sizes, int n_in,
                              void* d_out, int out_size, void* d_ws, size_t ws_size,
                              hipStream_t stream) {
    const int n = out_size;                  // 33,554,432 f32 elements
    const int nvec = n / 4;                  // 4 f32 per float4
    const int rem = n - nvec * 4;

    if (nvec > 0) {
        // 2048 blocks = 8 workgroups/CU on 256 CUs; each thread handles
        // nvec / (2048*256) = 16 float4s via grid-stride.
        int blocks = 2048;
        int needed = (nvec + 255) / 256;
        if (needed < blocks) blocks = needed;
        j_gridstride_kernel<<<blocks, 256, 0, stream>>>(
            (const f32x4*)d_in[0], (const f32x4*)d_in[1], (f32x4*)d_out, nvec);
    }
    if (rem > 0) {
        j_tail_kernel<<<1, 256, 0, stream>>>(
            (const float*)d_in[0], (const float*)d_in[1],
            (float*)d_out, nvec * 4, n);
    }
}

// Round 4
// 305.028 us; speedup vs baseline: 1.0226x; 1.0226x over previous
//
#include <hip/hip_runtime.h>

// j = 1 - log10(1024*|x-y| + 1), elementwise over float32 tensors.
// shape (8,16,4096,64) = 33,554,432 f32 elements per tensor (134.2 MB each).
//
// R3 post-mortem: nt-stores regressed (105->119us), FETCH unchanged. Reverted.
// R4 post-mortem: grid-stride regressed (105->115.5us); strided loop + bound
//   check defeated unrolling -> per-wave MLP stayed at 2 loads. Reverted.
//
// R5 theory: all variants sit at ~2.55 TB/s because each wave has only 2
// load instructions (2 KB) in flight before the vmcnt(0) stall. Little's law
// with ~900cy HBM latency matches the observed BW. Fix: straight-line batch
// of 8 independent dwordx4 loads per wave (4 block-strided float4s per
// thread), quadrupling in-flight bytes; also 16x fewer workgroups.
// Prediction: FETCH/WRITE unchanged, dispatch 105 -> ~65-80 us.

typedef float f32x4 __attribute__((ext_vector_type(4)));

__device__ __forceinline__ float j_elem(float xv, float yv) {
    float d = xv - yv;
    // sqrt(1024^2 * d^2) == 1024 * |d|
    float dist = 1024.0f * fabsf(d);
    // log10(v) = log2(v) * log10(2); v_log_f32 accuracy ~1 ulp, threshold 5.75e-2
    return 1.0f - 0.30102999566398120f * __log2f(dist + 1.0f);
}

__device__ __forceinline__ f32x4 j_vec(f32x4 xv, f32x4 yv) {
    f32x4 ov;
    ov.x = j_elem(xv.x, yv.x);
    ov.y = j_elem(xv.y, yv.y);
    ov.z = j_elem(xv.z, yv.z);
    ov.w = j_elem(xv.w, yv.w);
    return ov;
}

// Each block handles 1024 consecutive float4s: 256 threads x 4 float4s at
// block-stride 256 (per-instruction coalescing: lane i reads base+i*16B).
// All 8 loads are issued straight-line before any use -> 8 KB in flight
// per wave instead of 2 KB.
__global__ __launch_bounds__(256) void j_batch4_kernel(const f32x4* __restrict__ x,
                                                       const f32x4* __restrict__ y,
                                                       f32x4* __restrict__ out) {
    int base = blockIdx.x * 1024 + threadIdx.x;
    f32x4 x0 = x[base];
    f32x4 x1 = x[base + 256];
    f32x4 x2 = x[base + 512];
    f32x4 x3 = x[base + 768];
    f32x4 y0 = y[base];
    f32x4 y1 = y[base + 256];
    f32x4 y2 = y[base + 512];
    f32x4 y3 = y[base + 768];
    out[base]       = j_vec(x0, y0);
    out[base + 256] = j_vec(x1, y1);
    out[base + 512] = j_vec(x2, y2);
    out[base + 768] = j_vec(x3, y3);
}

// Cover any float4s past the batch region (none for the bench shape).
__global__ __launch_bounds__(256) void j_vec4_kernel(const f32x4* __restrict__ x,
                                                     const f32x4* __restrict__ y,
                                                     f32x4* __restrict__ out,
                                                     int start, int nvec) {
    int i = start + blockIdx.x * blockDim.x + threadIdx.x;
    if (i >= nvec) return;
    out[i] = j_vec(x[i], y[i]);
}

// Scalar tail for n % 4 (none for the bench shape).
__global__ __launch_bounds__(256) void j_tail_kernel(const float* __restrict__ x,
                                                     const float* __restrict__ y,
                                                     float* __restrict__ out,
                                                     int start, int n) {
    int i = start + blockIdx.x * blockDim.x + threadIdx.x;
    if (i >= n) return;
    out[i] = j_elem(x[i], y[i]);
}

extern "C" void kernel_launch(void* const* d_in, const int* in_sizes, int n_in,
                              void* d_out, int out_size, void* d_ws, size_t ws_size,
                              hipStream_t stream) {
    const int n = out_size;                  // 33,554,432 f32 elements
    const int nvec = n / 4;                  // float4 count
    const int rem = n - nvec * 4;

    const int V4_PER_BLOCK = 1024;           // 256 threads x 4 float4
    const int nblocks_batch = nvec / V4_PER_BLOCK;
    const int batched = nblocks_batch * V4_PER_BLOCK;

    if (nblocks_batch > 0) {
        j_batch4_kernel<<<nblocks_batch, 256, 0, stream>>>(
            (const f32x4*)d_in[0], (const f32x4*)d_in[1], (f32x4*)d_out);
    }
    if (batched < nvec) {
        int restv = nvec - batched;
        int blocks = (restv + 255) / 256;
        j_vec4_kernel<<<blocks, 256, 0, stream>>>(
            (const f32x4*)d_in[0], (const f32x4*)d_in[1], (f32x4*)d_out,
            batched, nvec);
    }
    if (rem > 0) {
        j_tail_kernel<<<1, 256, 0, stream>>>(
            (const float*)d_in[0], (const float*)d_in[1],
            (float*)d_out, nvec * 4, n);
    }
}

// Round 5
// 301.410 us; speedup vs baseline: 1.0349x; 1.0120x over previous
//
#include <hip/hip_runtime.h>

// j = 1 - log10(1024*|x-y| + 1), elementwise over float32 tensors.
// shape (8,16,4096,64) = 33,554,432 f32 elements per tensor (134.2 MB each).
//
// Session ledger:
//  R1 baseline (this structure, forward order): 105 us dispatch, 2.55 TB/s,
//     FETCH=WRITE=134 MB (harness poison of `out` evicts half of x+y from L3).
//  R3 nt-store: REGRESSED 119 us, FETCH unchanged -> L3 store-bypass has no
//     working mechanism from the kernel side. Reverted.
//  R4 grid-stride 2048 blocks: REGRESSED 115.5 us -> dispatch rate not limiter.
//  R5 batch4 (8 loads/wave in flight, 8192 blocks): REGRESSED 112 us ->
//     per-wave MLP not the limiter either. Reverted.
//
//  R6: revert to R1 structure + ONE probe: reverse block traversal. If the
//  L3-surviving input half is tail-biased (LRU-ish), consuming it first
//  avoids the forward-scan self-eviction pathology. Prediction: either
//  FETCH < 100 MB & ~90-95 us, or exact parity (-> roofline declared).

__device__ __forceinline__ float j_elem(float xv, float yv) {
    float d = xv - yv;
    // sqrt(1024^2 * d^2) == 1024 * |d|
    float dist = 1024.0f * fabsf(d);
    // log10(v) = log2(v) * log10(2); v_log_f32 accuracy ~1 ulp, threshold 5.75e-2
    return 1.0f - 0.30102999566398120f * __log2f(dist + 1.0f);
}

__global__ __launch_bounds__(256) void j_vec4_rev_kernel(const float4* __restrict__ x,
                                                         const float4* __restrict__ y,
                                                         float4* __restrict__ out,
                                                         int nvec) {
    // Reverse block order: block 0 handles the HIGHEST addresses.
    // Within-wave lane->address mapping unchanged (full coalescing).
    int rb = (int)gridDim.x - 1 - (int)blockIdx.x;
    int i = rb * (int)blockDim.x + (int)threadIdx.x;
    if (i >= nvec) return;
    float4 xv = x[i];
    float4 yv = y[i];
    float4 ov;
    ov.x = j_elem(xv.x, yv.x);
    ov.y = j_elem(xv.y, yv.y);
    ov.z = j_elem(xv.z, yv.z);
    ov.w = j_elem(xv.w, yv.w);
    out[i] = ov;
}

__global__ __launch_bounds__(256) void j_tail_kernel(const float* __restrict__ x,
                                                     const float* __restrict__ y,
                                                     float* __restrict__ out,
                                                     int start, int n) {
    int i = start + blockIdx.x * blockDim.x + threadIdx.x;
    if (i >= n) return;
    out[i] = j_elem(x[i], y[i]);
}

extern "C" void kernel_launch(void* const* d_in, const int* in_sizes, int n_in,
                              void* d_out, int out_size, void* d_ws, size_t ws_size,
                              hipStream_t stream) {
    const int n = out_size;                  // 33,554,432 f32 elements
    const int nvec = n / 4;                  // 4 f32 per float4
    const int rem = n - nvec * 4;

    if (nvec > 0) {
        int blocks = (nvec + 255) / 256;
        j_vec4_rev_kernel<<<blocks, 256, 0, stream>>>(
            (const float4*)d_in[0], (const float4*)d_in[1], (float4*)d_out, nvec);
    }
    if (rem > 0) {
        j_tail_kernel<<<1, 256, 0, stream>>>(
            (const float*)d_in[0], (const float*)d_in[1],
            (float*)d_out, nvec * 4, n);
    }
}